// Round 11
// baseline (395.641 us; speedup 1.0000x reference)
//
#include <hip/hip_runtime.h>

// ---------------------------------------------------------------------------
// Round 11: R10 stage-once conv + explicit software pipeline in the K-loop:
//   step s: issue ds_read B(s+1), global-load A(s+2), then MFMA(A(s),B(s)).
// Distinct register stages (a0,a1,a2 / b0,b1) rotated at step end; kk-loop
// unrolled 9x so rotation is renamed away. NC8HW8 bf16 activations, linear
// frag-order weights wTs[s][g][lane][8] (s = icb*9+kk). fp32 in / fp32 out.
// ---------------------------------------------------------------------------

typedef __attribute__((ext_vector_type(8))) short short8;
typedef __attribute__((ext_vector_type(4))) float floatx4;
typedef unsigned int uint;
typedef unsigned short ushort;

__device__ __forceinline__ ushort f2bf(float f) {
    uint u = __float_as_uint(f);
    return (ushort)((u + 0x7fffu + ((u >> 16) & 1u)) >> 16);
}
__device__ __forceinline__ float bf2f(ushort h) {
    return __uint_as_float(((uint)h) << 16);
}

// ---------------- weight transform: w[OC][IC][3][3] fp32 -> linear frag order
// dst[((icb*9+kk)*G16 + g)*64 + lane][8]: oc=g*16+(lane&15), ic=icb*32+(lane>>4)*8+j
__global__ __launch_bounds__(256) void wtransform_lin(
    const float* __restrict__ src, short* __restrict__ dst, int OC, int IC)
{
    int n = 9 * OC * IC;
    int o = blockIdx.x * 256 + threadIdx.x;
    if (o >= n) return;
    int j    = o & 7;
    int lane = (o >> 3) & 63;
    int r    = o >> 9;
    int G16  = OC >> 4;
    int g    = r % G16;  r /= G16;
    int kk   = r % 9;
    int icb  = r / 9;
    int oc = g * 16 + (lane & 15);
    int ic = icb * 32 + (lane >> 4) * 8 + j;
    dst[o] = (short)f2bf(src[((long)oc * IC + ic) * 9 + kk]);
}

// conv0 weights: w0[64][3][3][3] fp32 -> wT0[64][32] bf16 (k = c*9+ky*3+kx, pad 0)
__global__ __launch_bounds__(256) void wtransform0(
    const float* __restrict__ src, short* __restrict__ dst)
{
    int idx = blockIdx.x * 256 + threadIdx.x;
    if (idx >= 64 * 32) return;
    int oc = idx >> 5, k = idx & 31;
    dst[idx] = (k < 27) ? (short)f2bf(src[oc * 27 + k]) : (short)0;
}

// ---------------- conv0 MFMA: 3->64 @32x32, NCHW fp32 in, NC8HW8 bf16 out
__global__ __launch_bounds__(256, 2) void conv0_mfma(
    const float* __restrict__ x, const short* __restrict__ wT0,
    const float* __restrict__ b0, ushort* __restrict__ out)
{
    __shared__ float  s_x[3 * 18 * 34];
    __shared__ ushort s_b[4 * 512 * 8];

    const int tid  = threadIdx.x;
    const int wv   = tid >> 6;
    const int lane = tid & 63;
    const int quad = lane >> 4;
    const int l16  = lane & 15;
    const int b    = blockIdx.x >> 1;
    const int r0   = (blockIdx.x & 1) * 16;

    for (int idx = tid; idx < 3 * 18 * 34; idx += 256) {
        int c   = idx / 612;
        int rem = idx - c * 612;
        int ry  = rem / 34, rx = rem - ry * 34;
        int gy  = r0 + ry - 1, gx = rx - 1;
        float v = 0.f;
        if (gy >= 0 && gy < 32 && gx >= 0 && gx < 32)
            v = x[(((long)b * 3 + c) * 32 + gy) * 32 + gx];
        s_x[idx] = v;
    }
    __syncthreads();

#pragma unroll
    for (int rep = 0; rep < 2; ++rep) {
        int pxl = rep * 256 + tid;
        int py = pxl >> 5, px = pxl & 31;
        ushort v[32];
#pragma unroll
        for (int c = 0; c < 3; ++c)
#pragma unroll
            for (int ky = 0; ky < 3; ++ky)
#pragma unroll
                for (int kx = 0; kx < 3; ++kx)
                    v[c * 9 + ky * 3 + kx] = f2bf(s_x[c * 612 + (py + ky) * 34 + (px + kx)]);
#pragma unroll
        for (int k = 27; k < 32; ++k) v[k] = 0;
#pragma unroll
        for (int q = 0; q < 4; ++q)
            *(uint4*)(&s_b[(q * 512 + pxl) * 8]) = *(const uint4*)(v + q * 8);
    }
    __syncthreads();

    floatx4 acc[4][8];
#pragma unroll
    for (int i = 0; i < 4; ++i)
#pragma unroll
        for (int t = 0; t < 8; ++t) acc[i][t] = (floatx4)0.f;

    short8 afr[4];
#pragma unroll
    for (int i = 0; i < 4; ++i)
        afr[i] = *(const short8*)(wT0 + (i * 16 + l16) * 32 + quad * 8);
#pragma unroll
    for (int t = 0; t < 8; ++t) {
        int pxl = wv * 128 + t * 16 + l16;
        short8 bfr = *(const short8*)(&s_b[(quad * 512 + pxl) * 8]);
#pragma unroll
        for (int i = 0; i < 4; ++i)
            acc[i][t] = __builtin_amdgcn_mfma_f32_16x16x32_bf16(afr[i], bfr, acc[i][t], 0, 0, 0);
    }

#pragma unroll
    for (int i = 0; i < 4; ++i) {
        int oc0 = i * 16 + quad * 4;
        float4 bv = *(const float4*)(b0 + oc0);
#pragma unroll
        for (int t = 0; t < 8; ++t) {
            int pxl = wv * 128 + t * 16 + l16;
            int py = pxl >> 5, px = pxl & 31;
            long dst = ((((long)b * 8 + (oc0 >> 3)) * 32 + r0 + py) * 32 + px) * 8 + (oc0 & 7);
            float v0 = acc[i][t][0] + bv.x;
            float v1 = acc[i][t][1] + bv.y;
            float v2 = acc[i][t][2] + bv.z;
            float v3 = acc[i][t][3] + bv.w;
            ushort o[4];
            o[0] = f2bf(v0 > 0.f ? v0 : 0.f);
            o[1] = f2bf(v1 > 0.f ? v1 : 0.f);
            o[2] = f2bf(v2 > 0.f ? v2 : 0.f);
            o[3] = f2bf(v3 > 0.f ? v3 : 0.f);
            *(uint2*)(out + dst) = *(uint2*)o;
        }
    }
}

// ---------------- stage-once conv3x3+ReLU, NC8HW8 in/out, pipelined K-loop
template<int IC, int OC, int H, int W, int ROWS, int OCGROUPS>
__global__ __launch_bounds__(256, 2) void conv_so(
    const ushort* __restrict__ act_in,  // [B][IC/8][H][W][8]
    const short*  __restrict__ wTs,     // linear frag-order bf16
    const float*  __restrict__ bias,
    ushort* __restrict__ act_out)       // [B][OC/8][H][W][8]
{
    constexpr int WPAD  = W + 2;
    constexpr int RPAD  = ROWS + 2;
    constexpr int UNITS = RPAD * WPAD;
    constexpr int SEGS  = H / ROWS;
    constexpr int C8I   = IC / 8;
    constexpr int CPUP  = C8I + 1;        // odd -> bank spread
    constexpr int G16   = OC / 16;
    constexpr int NICB  = IC / 32;
    constexpr int C8O   = OC / 8;
    constexpr int TMAX  = NICB * 9;

    __shared__ ushort s_act[UNITS * CPUP * 8];

    const int tid  = threadIdx.x;
    const int wv   = tid >> 6;
    const int lane = tid & 63;
    const int quad = lane >> 4;
    const int l16  = lane & 15;

    const int b   = blockIdx.x / SEGS;
    const int seg = blockIdx.x - b * SEGS;
    const int r0  = seg * ROWS;
    const int ocg = wv % OCGROUPS;
    const int pxg = wv / OCGROUPS;

    // ---- stage entire haloed strip, all IC, once ----
    for (int c = tid; c < UNITS * C8I; c += 256) {
        int sub  = c / UNITS;
        int unit = c - sub * UNITS;
        int ry   = unit / WPAD, cx = unit - ry * WPAD;
        int gy   = r0 + ry - 1, gx = cx - 1;
        uint4 val = make_uint4(0, 0, 0, 0);
        if ((unsigned)gy < (unsigned)H && (unsigned)gx < (unsigned)W) {
            long src = ((((long)b * C8I + sub) * H + gy) * W + gx) * 8;
            val = *(const uint4*)(act_in + src);
        }
        *(uint4*)(&s_act[((size_t)unit * CPUP + sub) * 8]) = val;
    }
    __syncthreads();
    // ---- no barriers below this line ----

    floatx4 acc[4][4];
#pragma unroll
    for (int i = 0; i < 4; ++i)
#pragma unroll
        for (int t = 0; t < 4; ++t) acc[i][t] = (floatx4)0.f;

    int bbase[4];
#pragma unroll
    for (int t = 0; t < 4; ++t) {
        int pxl = pxg * 64 + t * 16 + l16;
        int py  = pxl / W, px = pxl - py * W;
        bbase[t] = (py * WPAD + px) * CPUP * 8;
    }

    const short8* wb = (const short8*)wTs;
    const int abase = ocg * 4;

    // register pipeline stages
    short8 a0[4], a1[4], a2[4], bf0[4], bf1[4];
#pragma unroll
    for (int i = 0; i < 4; ++i) {
        a0[i] = wb[((long)0 * G16 + abase + i) * 64 + lane];
        a1[i] = wb[((long)1 * G16 + abase + i) * 64 + lane];
    }
#pragma unroll
    for (int t = 0; t < 4; ++t)   // B for step 0: kk=0 -> ky=0,kx=0, icb=0
        bf0[t] = *(const short8*)(&s_act[bbase[t] + quad * 8]);

    for (int icb = 0; icb < NICB; ++icb) {
#pragma unroll
        for (int kk = 0; kk < 9; ++kk) {
            // ---- issue B reads for step s+1 ----
            const int kkn  = (kk + 1) % 9;                      // unroll-const
            const int kyn  = kkn / 3, kxn = kkn - kyn * 3;
            const int icbn = (kk == 8) ? ((icb + 1 < NICB) ? icb + 1 : icb) : icb;
            const int koffN = ((kyn * WPAD + kxn) * CPUP + icbn * 4 + quad) * 8;
#pragma unroll
            for (int t = 0; t < 4; ++t)
                bf1[t] = *(const short8*)(&s_act[bbase[t] + koffN]);
            // ---- issue A loads for step s+2 ----
            int s2 = icb * 9 + kk + 2;
            if (s2 >= TMAX) s2 = TMAX - 1;
#pragma unroll
            for (int i = 0; i < 4; ++i)
                a2[i] = wb[((long)s2 * G16 + abase + i) * 64 + lane];
            // ---- MFMA with stage-0 data ----
#pragma unroll
            for (int i = 0; i < 4; ++i)
#pragma unroll
                for (int t = 0; t < 4; ++t)
                    acc[i][t] = __builtin_amdgcn_mfma_f32_16x16x32_bf16(
                        a0[i], bf0[t], acc[i][t], 0, 0, 0);
            // ---- rotate stages ----
#pragma unroll
            for (int i = 0; i < 4; ++i) { a0[i] = a1[i]; a1[i] = a2[i]; }
#pragma unroll
            for (int t = 0; t < 4; ++t) bf0[t] = bf1[t];
        }
    }

#pragma unroll
    for (int i = 0; i < 4; ++i) {
        int oc0 = ocg * 64 + i * 16 + quad * 4;
        float4 bv = *(const float4*)(bias + oc0);
#pragma unroll
        for (int t = 0; t < 4; ++t) {
            int pxl = pxg * 64 + t * 16 + l16;
            int py  = pxl / W, px = pxl - py * W;
            long dst = ((((long)b * C8O + (oc0 >> 3)) * H + r0 + py) * W + px) * 8 + (oc0 & 7);
            float v0 = acc[i][t][0] + bv.x;
            float v1 = acc[i][t][1] + bv.y;
            float v2 = acc[i][t][2] + bv.z;
            float v3 = acc[i][t][3] + bv.w;
            ushort o[4];
            o[0] = f2bf(v0 > 0.f ? v0 : 0.f);
            o[1] = f2bf(v1 > 0.f ? v1 : 0.f);
            o[2] = f2bf(v2 > 0.f ? v2 : 0.f);
            o[3] = f2bf(v3 > 0.f ? v3 : 0.f);
            *(uint2*)(act_out + dst) = *(uint2*)o;
        }
    }
}

// ---------------- maxpool 2x2, NC8HW8 bf16 (post-ReLU: integer max valid)
template<int C8>
__global__ __launch_bounds__(256) void maxpool_c8(
    const ushort* __restrict__ in, ushort* __restrict__ out,
    int total, int HO, int WO)
{
    int idx = blockIdx.x * 256 + threadIdx.x;
    if (idx >= total) return;                    // total = B*C8*HO*WO
    int xo = idx % WO;
    int t  = idx / WO;
    int yo = t % HO;  t /= HO;
    int c8 = t % C8;
    int b  = t / C8;
    const int WI = 2 * WO, HI = 2 * HO;
    const ushort* base = in + ((((long)b * C8 + c8) * HI + 2 * yo) * WI + 2 * xo) * 8;
    uint4 q0 = *(const uint4*)(base);
    uint4 q1 = *(const uint4*)(base + 8);
    uint4 q2 = *(const uint4*)(base + (long)WI * 8);
    uint4 q3 = *(const uint4*)(base + (long)WI * 8 + 8);
    const ushort* a0 = (const ushort*)&q0;
    const ushort* a1 = (const ushort*)&q1;
    const ushort* a2 = (const ushort*)&q2;
    const ushort* a3 = (const ushort*)&q3;
    ushort r[8];
#pragma unroll
    for (int j = 0; j < 8; ++j) {
        ushort m0 = a0[j] > a1[j] ? a0[j] : a1[j];
        ushort m1 = a2[j] > a3[j] ? a2[j] : a3[j];
        r[j] = m0 > m1 ? m0 : m1;
    }
    *(uint4*)(out + (long)idx * 8) = *(uint4*)r;
}

// ---------------- classifier: wave per (b, class); feat [b][c8][y][x][8]
// reference flatten d = ch*16 + p (p=y*4+x): c8=d>>7, j=(d>>4)&7, p=d&15
__global__ __launch_bounds__(256) void classifier_k(
    const ushort* __restrict__ feat, const int* __restrict__ tids,
    const float* __restrict__ cw, const float* __restrict__ cb,
    float* __restrict__ out, int B)
{
    int g = blockIdx.x * 256 + threadIdx.x;
    int wid = g >> 6, lane = g & 63;
    if (wid >= B * 5) return;
    int b = wid / 5, c = wid - b * 5;
    int t = tids[b];
    const float* wrow = cw + (long)(t * 5 + c) * 4096;
    const ushort* f = feat + (long)b * 4096;
    float s = 0.f;
#pragma unroll 4
    for (int d = lane; d < 4096; d += 64) {
        int fidx = (((d >> 7) * 16) + (d & 15)) * 8 + ((d >> 4) & 7);
        s += wrow[d] * bf2f(f[fidx]);
    }
#pragma unroll
    for (int off = 32; off > 0; off >>= 1) s += __shfl_down(s, off, 64);
    if (lane == 0) out[wid] = s + cb[t * 5 + c];
}

// ---------------------------------------------------------------------------
extern "C" void kernel_launch(void* const* d_in, const int* in_sizes, int n_in,
                              void* d_out, int out_size, void* d_ws, size_t ws_size,
                              hipStream_t stream)
{
    const float* x   = (const float*)d_in[0];
    const int*   tid = (const int*)d_in[1];
    const float* w0 = (const float*)d_in[2];  const float* b0 = (const float*)d_in[3];
    const float* w1 = (const float*)d_in[4];  const float* b1 = (const float*)d_in[5];
    const float* w2 = (const float*)d_in[6];  const float* b2 = (const float*)d_in[7];
    const float* w3 = (const float*)d_in[8];  const float* b3 = (const float*)d_in[9];
    const float* w4 = (const float*)d_in[10]; const float* b4 = (const float*)d_in[11];
    const float* w5 = (const float*)d_in[12]; const float* b5 = (const float*)d_in[13];
    const float* cw = (const float*)d_in[14];
    const float* cb = (const float*)d_in[15];
    float* outp = (float*)d_out;

    const int B = in_sizes[0] / (3 * 32 * 32);   // 512

    // ---- ws layout (halfword units) ----
    short* wt0  = (short*)d_ws;                   // 64*32      = 2048
    short* wts1 = wt0 + 2048;                     // 9*64*64    = 36864
    short* wts2 = wts1 + 36864;                   // 9*128*64   = 73728
    short* wts3 = wts2 + 73728;                   // 9*128*128  = 147456
    short* wts4 = wts3 + 147456;                  // 9*256*128  = 294912
    short* wts5 = wts4 + 294912;                  // 9*256*256  = 589824
    const size_t WT_HW = 2048 + 36864 + 73728 + 147456 + 294912 + 589824;
    const size_t fixed_bytes = WT_HW * 2;

    int Bc = B;
    while (Bc > 2 && fixed_bytes + (size_t)Bc * 2 * 65536 * 2 > ws_size) Bc >>= 1;
    if (Bc < 2) Bc = 2;

    ushort* bufA = (ushort*)((short*)d_ws + WT_HW);
    ushort* bufB = bufA + (size_t)Bc * 65536;

    // ---- weight transforms (every launch; ws is re-poisoned) ----
    wtransform0<<<(64 * 32 + 255) / 256, 256, 0, stream>>>(w0, wt0);
    wtransform_lin<<<(9 * 64 * 64 + 255) / 256, 256, 0, stream>>>(w1, wts1, 64, 64);
    wtransform_lin<<<(9 * 128 * 64 + 255) / 256, 256, 0, stream>>>(w2, wts2, 128, 64);
    wtransform_lin<<<(9 * 128 * 128 + 255) / 256, 256, 0, stream>>>(w3, wts3, 128, 128);
    wtransform_lin<<<(9 * 256 * 128 + 255) / 256, 256, 0, stream>>>(w4, wts4, 256, 128);
    wtransform_lin<<<(9 * 256 * 256 + 255) / 256, 256, 0, stream>>>(w5, wts5, 256, 256);

    for (int cb0 = 0; cb0 < B; cb0 += Bc) {
        const float* xc = x + (size_t)cb0 * 3 * 32 * 32;
        const int* tidc = tid + cb0;
        float* outc = outp + (size_t)cb0 * 5;

        // conv0: 3->64 @32x32 -> [Bc][8][32][32][8]
        conv0_mfma<<<Bc * 2, 256, 0, stream>>>(xc, wt0, b0, bufA);
        // conv1: 64->64 @32x32, ROWS=8, 4 pxg  (grid Bc*4)
        conv_so<64, 64, 32, 32, 8, 1><<<Bc * 4, 256, 0, stream>>>(bufA, wts1, b1, bufB);
        // pool -> [Bc][8][16][16][8]
        maxpool_c8<8><<<(Bc * 8 * 16 * 16 + 255) / 256, 256, 0, stream>>>(bufB, bufA, Bc * 8 * 16 * 16, 16, 16);
        // conv2: 64->128 @16x16, ROWS=8, 2 ocg x 2 pxg  (grid Bc*2)
        conv_so<64, 128, 16, 16, 8, 2><<<Bc * 2, 256, 0, stream>>>(bufA, wts2, b2, bufB);
        // conv3: 128->128 @16x16
        conv_so<128, 128, 16, 16, 8, 2><<<Bc * 2, 256, 0, stream>>>(bufB, wts3, b3, bufA);
        // pool -> [Bc][16][8][8][8]
        maxpool_c8<16><<<(Bc * 16 * 8 * 8 + 255) / 256, 256, 0, stream>>>(bufA, bufB, Bc * 16 * 8 * 8, 8, 8);
        // conv4: 128->256 @8x8, ROWS=8 (full), 4 ocg  (grid Bc)
        conv_so<128, 256, 8, 8, 8, 4><<<Bc, 256, 0, stream>>>(bufB, wts4, b4, bufA);
        // conv5: 256->256 @8x8
        conv_so<256, 256, 8, 8, 8, 4><<<Bc, 256, 0, stream>>>(bufA, wts5, b5, bufB);
        // pool -> [Bc][32][4][4][8]
        maxpool_c8<32><<<(Bc * 32 * 4 * 4 + 255) / 256, 256, 0, stream>>>(bufB, bufA, Bc * 32 * 4 * 4, 4, 4);
        // classifier
        classifier_k<<<(Bc * 5 * 64 + 255) / 256, 256, 0, stream>>>(bufA, tidc, cw, cb, outc, Bc);
    }
}

// Round 12
// 314.218 us; speedup vs baseline: 1.2591x; 1.2591x over previous
//
#include <hip/hip_runtime.h>

// ---------------------------------------------------------------------------
// Round 12: R10 stage-once conv (reverted from R11's regressive SW pipeline)
// + fused 2x2 maxpool epilogues on conv1/3/5 (LDS round-trip, integer max).
// NC8HW8 bf16 activations, linear frag-order weights, fp32 in / fp32 out.
// ---------------------------------------------------------------------------

typedef __attribute__((ext_vector_type(8))) short short8;
typedef __attribute__((ext_vector_type(4))) float floatx4;
typedef unsigned int uint;
typedef unsigned short ushort;

__device__ __forceinline__ ushort f2bf(float f) {
    uint u = __float_as_uint(f);
    return (ushort)((u + 0x7fffu + ((u >> 16) & 1u)) >> 16);
}
__device__ __forceinline__ float bf2f(ushort h) {
    return __uint_as_float(((uint)h) << 16);
}

// ---------------- weight transform: w[OC][IC][3][3] fp32 -> linear frag order
// dst[((icb*9+kk)*G16 + g)*64 + lane][8]: oc=g*16+(lane&15), ic=icb*32+(lane>>4)*8+j
__global__ __launch_bounds__(256) void wtransform_lin(
    const float* __restrict__ src, short* __restrict__ dst, int OC, int IC)
{
    int n = 9 * OC * IC;
    int o = blockIdx.x * 256 + threadIdx.x;
    if (o >= n) return;
    int j    = o & 7;
    int lane = (o >> 3) & 63;
    int r    = o >> 9;
    int G16  = OC >> 4;
    int g    = r % G16;  r /= G16;
    int kk   = r % 9;
    int icb  = r / 9;
    int oc = g * 16 + (lane & 15);
    int ic = icb * 32 + (lane >> 4) * 8 + j;
    dst[o] = (short)f2bf(src[((long)oc * IC + ic) * 9 + kk]);
}

// conv0 weights: w0[64][3][3][3] fp32 -> wT0[64][32] bf16 (k = c*9+ky*3+kx, pad 0)
__global__ __launch_bounds__(256) void wtransform0(
    const float* __restrict__ src, short* __restrict__ dst)
{
    int idx = blockIdx.x * 256 + threadIdx.x;
    if (idx >= 64 * 32) return;
    int oc = idx >> 5, k = idx & 31;
    dst[idx] = (k < 27) ? (short)f2bf(src[oc * 27 + k]) : (short)0;
}

// ---------------- conv0 MFMA: 3->64 @32x32, NCHW fp32 in, NC8HW8 bf16 out
__global__ __launch_bounds__(256, 2) void conv0_mfma(
    const float* __restrict__ x, const short* __restrict__ wT0,
    const float* __restrict__ b0, ushort* __restrict__ out)
{
    __shared__ float  s_x[3 * 18 * 34];
    __shared__ ushort s_b[4 * 512 * 8];

    const int tid  = threadIdx.x;
    const int wv   = tid >> 6;
    const int lane = tid & 63;
    const int quad = lane >> 4;
    const int l16  = lane & 15;
    const int b    = blockIdx.x >> 1;
    const int r0   = (blockIdx.x & 1) * 16;

    for (int idx = tid; idx < 3 * 18 * 34; idx += 256) {
        int c   = idx / 612;
        int rem = idx - c * 612;
        int ry  = rem / 34, rx = rem - ry * 34;
        int gy  = r0 + ry - 1, gx = rx - 1;
        float v = 0.f;
        if (gy >= 0 && gy < 32 && gx >= 0 && gx < 32)
            v = x[(((long)b * 3 + c) * 32 + gy) * 32 + gx];
        s_x[idx] = v;
    }
    __syncthreads();

#pragma unroll
    for (int rep = 0; rep < 2; ++rep) {
        int pxl = rep * 256 + tid;
        int py = pxl >> 5, px = pxl & 31;
        ushort v[32];
#pragma unroll
        for (int c = 0; c < 3; ++c)
#pragma unroll
            for (int ky = 0; ky < 3; ++ky)
#pragma unroll
                for (int kx = 0; kx < 3; ++kx)
                    v[c * 9 + ky * 3 + kx] = f2bf(s_x[c * 612 + (py + ky) * 34 + (px + kx)]);
#pragma unroll
        for (int k = 27; k < 32; ++k) v[k] = 0;
#pragma unroll
        for (int q = 0; q < 4; ++q)
            *(uint4*)(&s_b[(q * 512 + pxl) * 8]) = *(const uint4*)(v + q * 8);
    }
    __syncthreads();

    floatx4 acc[4][8];
#pragma unroll
    for (int i = 0; i < 4; ++i)
#pragma unroll
        for (int t = 0; t < 8; ++t) acc[i][t] = (floatx4)0.f;

    short8 afr[4];
#pragma unroll
    for (int i = 0; i < 4; ++i)
        afr[i] = *(const short8*)(wT0 + (i * 16 + l16) * 32 + quad * 8);
#pragma unroll
    for (int t = 0; t < 8; ++t) {
        int pxl = wv * 128 + t * 16 + l16;
        short8 bfr = *(const short8*)(&s_b[(quad * 512 + pxl) * 8]);
#pragma unroll
        for (int i = 0; i < 4; ++i)
            acc[i][t] = __builtin_amdgcn_mfma_f32_16x16x32_bf16(afr[i], bfr, acc[i][t], 0, 0, 0);
    }

#pragma unroll
    for (int i = 0; i < 4; ++i) {
        int oc0 = i * 16 + quad * 4;
        float4 bv = *(const float4*)(b0 + oc0);
#pragma unroll
        for (int t = 0; t < 8; ++t) {
            int pxl = wv * 128 + t * 16 + l16;
            int py = pxl >> 5, px = pxl & 31;
            long dst = ((((long)b * 8 + (oc0 >> 3)) * 32 + r0 + py) * 32 + px) * 8 + (oc0 & 7);
            float v0 = acc[i][t][0] + bv.x;
            float v1 = acc[i][t][1] + bv.y;
            float v2 = acc[i][t][2] + bv.z;
            float v3 = acc[i][t][3] + bv.w;
            ushort o[4];
            o[0] = f2bf(v0 > 0.f ? v0 : 0.f);
            o[1] = f2bf(v1 > 0.f ? v1 : 0.f);
            o[2] = f2bf(v2 > 0.f ? v2 : 0.f);
            o[3] = f2bf(v3 > 0.f ? v3 : 0.f);
            *(uint2*)(out + dst) = *(uint2*)o;
        }
    }
}

// ---------------- stage-once conv3x3+ReLU (+optional fused 2x2 maxpool)
// Block = 4 waves, one strip of ROWS rows. Wave = 64 oc x 64 px (4x4 frags).
template<int IC, int OC, int H, int W, int ROWS, int OCGROUPS, bool POOL>
__global__ __launch_bounds__(256, 2) void conv_so(
    const ushort* __restrict__ act_in,  // [B][IC/8][H][W][8]
    const short*  __restrict__ wTs,     // linear frag-order bf16
    const float*  __restrict__ bias,
    ushort* __restrict__ act_out)       // [B][OC/8][H'][W'][8] (pooled if POOL)
{
    constexpr int WPAD  = W + 2;
    constexpr int RPAD  = ROWS + 2;
    constexpr int UNITS = RPAD * WPAD;
    constexpr int SEGS  = H / ROWS;
    constexpr int C8I   = IC / 8;
    constexpr int CPUP  = C8I + 1;        // odd -> bank spread
    constexpr int G16   = OC / 16;
    constexpr int NICB  = IC / 32;
    constexpr int C8O   = OC / 8;
    constexpr int TMAX  = NICB * 9;

    __shared__ ushort s_act[UNITS * CPUP * 8];

    const int tid  = threadIdx.x;
    const int wv   = tid >> 6;
    const int lane = tid & 63;
    const int quad = lane >> 4;
    const int l16  = lane & 15;

    const int b   = blockIdx.x / SEGS;
    const int seg = blockIdx.x - b * SEGS;
    const int r0  = seg * ROWS;
    const int ocg = wv % OCGROUPS;
    const int pxg = wv / OCGROUPS;

    // ---- stage entire haloed strip, all IC, once ----
    for (int c = tid; c < UNITS * C8I; c += 256) {
        int sub  = c / UNITS;
        int unit = c - sub * UNITS;
        int ry   = unit / WPAD, cx = unit - ry * WPAD;
        int gy   = r0 + ry - 1, gx = cx - 1;
        uint4 val = make_uint4(0, 0, 0, 0);
        if ((unsigned)gy < (unsigned)H && (unsigned)gx < (unsigned)W) {
            long src = ((((long)b * C8I + sub) * H + gy) * W + gx) * 8;
            val = *(const uint4*)(act_in + src);
        }
        *(uint4*)(&s_act[((size_t)unit * CPUP + sub) * 8]) = val;
    }
    __syncthreads();

    floatx4 acc[4][4];
#pragma unroll
    for (int i = 0; i < 4; ++i)
#pragma unroll
        for (int t = 0; t < 4; ++t) acc[i][t] = (floatx4)0.f;

    int bbase[4];
#pragma unroll
    for (int t = 0; t < 4; ++t) {
        int pxl = pxg * 64 + t * 16 + l16;
        int py  = pxl / W, px = pxl - py * W;
        bbase[t] = (py * WPAD + px) * CPUP * 8;
    }

    const short8* wb = (const short8*)wTs;
    short8 afr[4];
#pragma unroll
    for (int i = 0; i < 4; ++i)
        afr[i] = wb[((long)0 * G16 + ocg * 4 + i) * 64 + lane];

    int tl = 0;
    for (int icb = 0; icb < NICB; ++icb) {
#pragma unroll
        for (int kk = 0; kk < 9; ++kk) {
            const int ky = kk / 3, kx = kk - ky * 3;
            const int koff = ((ky * WPAD + kx) * CPUP + icb * 4 + quad) * 8;
            short8 bfr[4];
#pragma unroll
            for (int t = 0; t < 4; ++t)
                bfr[t] = *(const short8*)(&s_act[bbase[t] + koff]);
            int tn = (tl + 1 < TMAX) ? tl + 1 : tl;
            short8 afrN[4];
#pragma unroll
            for (int i = 0; i < 4; ++i)
                afrN[i] = wb[((long)tn * G16 + ocg * 4 + i) * 64 + lane];
#pragma unroll
            for (int i = 0; i < 4; ++i)
#pragma unroll
                for (int t = 0; t < 4; ++t)
                    acc[i][t] = __builtin_amdgcn_mfma_f32_16x16x32_bf16(
                        afr[i], bfr[t], acc[i][t], 0, 0, 0);
#pragma unroll
            for (int i = 0; i < 4; ++i) afr[i] = afrN[i];
            ++tl;
        }
    }

    if constexpr (!POOL) {
#pragma unroll
        for (int i = 0; i < 4; ++i) {
            int oc0 = ocg * 64 + i * 16 + quad * 4;
            float4 bv = *(const float4*)(bias + oc0);
#pragma unroll
            for (int t = 0; t < 4; ++t) {
                int pxl = pxg * 64 + t * 16 + l16;
                int py  = pxl / W, px = pxl - py * W;
                long dst = ((((long)b * C8O + (oc0 >> 3)) * H + r0 + py) * W + px) * 8 + (oc0 & 7);
                float v0 = acc[i][t][0] + bv.x;
                float v1 = acc[i][t][1] + bv.y;
                float v2 = acc[i][t][2] + bv.z;
                float v3 = acc[i][t][3] + bv.w;
                ushort o[4];
                o[0] = f2bf(v0 > 0.f ? v0 : 0.f);
                o[1] = f2bf(v1 > 0.f ? v1 : 0.f);
                o[2] = f2bf(v2 > 0.f ? v2 : 0.f);
                o[3] = f2bf(v3 > 0.f ? v3 : 0.f);
                *(uint2*)(act_out + dst) = *(uint2*)o;
            }
        }
    } else {
        // ---- fused 2x2 maxpool epilogue via LDS round-trip ----
        __syncthreads();                  // all waves done reading s_act
        ushort* s_pool = s_act;
        constexpr int PSTR = OC + 8;      // multiple of 8 -> 16B-aligned chunks
        static_assert(ROWS * W * PSTR <= UNITS * CPUP * 8, "pool scratch fits");
#pragma unroll
        for (int i = 0; i < 4; ++i) {
            int oc0 = ocg * 64 + i * 16 + quad * 4;
            float4 bv = *(const float4*)(bias + oc0);
#pragma unroll
            for (int t = 0; t < 4; ++t) {
                int pxl = pxg * 64 + t * 16 + l16;
                float v0 = acc[i][t][0] + bv.x;
                float v1 = acc[i][t][1] + bv.y;
                float v2 = acc[i][t][2] + bv.z;
                float v3 = acc[i][t][3] + bv.w;
                ushort o[4];
                o[0] = f2bf(v0 > 0.f ? v0 : 0.f);
                o[1] = f2bf(v1 > 0.f ? v1 : 0.f);
                o[2] = f2bf(v2 > 0.f ? v2 : 0.f);
                o[3] = f2bf(v3 > 0.f ? v3 : 0.f);
                *(uint2*)(&s_pool[pxl * PSTR + oc0]) = *(uint2*)o;
            }
        }
        __syncthreads();
        constexpr int PH = ROWS / 2, PW = W / 2, HOT = H / 2;
        const int pr0 = r0 / 2;
        for (int u = tid; u < PH * PW * C8O; u += 256) {
            int c8 = u % C8O;
            int pp = u / C8O;
            int xo = pp % PW, yo = pp / PW;
            const ushort* p00 = &s_pool[((2 * yo) * W + 2 * xo) * PSTR + c8 * 8];
            uint4 q0 = *(const uint4*)(p00);
            uint4 q1 = *(const uint4*)(p00 + PSTR);
            uint4 q2 = *(const uint4*)(p00 + W * PSTR);
            uint4 q3 = *(const uint4*)(p00 + W * PSTR + PSTR);
            const ushort* a0 = (const ushort*)&q0;
            const ushort* a1 = (const ushort*)&q1;
            const ushort* a2 = (const ushort*)&q2;
            const ushort* a3 = (const ushort*)&q3;
            ushort r[8];
#pragma unroll
            for (int j = 0; j < 8; ++j) {
                ushort m0 = a0[j] > a1[j] ? a0[j] : a1[j];
                ushort m1 = a2[j] > a3[j] ? a2[j] : a3[j];
                r[j] = m0 > m1 ? m0 : m1;
            }
            long dst = ((((long)b * C8O + c8) * HOT + pr0 + yo) * PW + xo) * 8;
            *(uint4*)(act_out + dst) = *(uint4*)r;
        }
    }
}

// ---------------- classifier: wave per (b, class); feat [b][c8][y][x][8]
// reference flatten d = ch*16 + p (p=y*4+x): c8=d>>7, j=(d>>4)&7, p=d&15
__global__ __launch_bounds__(256) void classifier_k(
    const ushort* __restrict__ feat, const int* __restrict__ tids,
    const float* __restrict__ cw, const float* __restrict__ cb,
    float* __restrict__ out, int B)
{
    int g = blockIdx.x * 256 + threadIdx.x;
    int wid = g >> 6, lane = g & 63;
    if (wid >= B * 5) return;
    int b = wid / 5, c = wid - b * 5;
    int t = tids[b];
    const float* wrow = cw + (long)(t * 5 + c) * 4096;
    const ushort* f = feat + (long)b * 4096;
    float s = 0.f;
#pragma unroll 4
    for (int d = lane; d < 4096; d += 64) {
        int fidx = (((d >> 7) * 16) + (d & 15)) * 8 + ((d >> 4) & 7);
        s += wrow[d] * bf2f(f[fidx]);
    }
#pragma unroll
    for (int off = 32; off > 0; off >>= 1) s += __shfl_down(s, off, 64);
    if (lane == 0) out[wid] = s + cb[t * 5 + c];
}

// ---------------------------------------------------------------------------
extern "C" void kernel_launch(void* const* d_in, const int* in_sizes, int n_in,
                              void* d_out, int out_size, void* d_ws, size_t ws_size,
                              hipStream_t stream)
{
    const float* x   = (const float*)d_in[0];
    const int*   tid = (const int*)d_in[1];
    const float* w0 = (const float*)d_in[2];  const float* b0 = (const float*)d_in[3];
    const float* w1 = (const float*)d_in[4];  const float* b1 = (const float*)d_in[5];
    const float* w2 = (const float*)d_in[6];  const float* b2 = (const float*)d_in[7];
    const float* w3 = (const float*)d_in[8];  const float* b3 = (const float*)d_in[9];
    const float* w4 = (const float*)d_in[10]; const float* b4 = (const float*)d_in[11];
    const float* w5 = (const float*)d_in[12]; const float* b5 = (const float*)d_in[13];
    const float* cw = (const float*)d_in[14];
    const float* cb = (const float*)d_in[15];
    float* outp = (float*)d_out;

    const int B = in_sizes[0] / (3 * 32 * 32);   // 512

    // ---- ws layout (halfword units) ----
    short* wt0  = (short*)d_ws;                   // 64*32      = 2048
    short* wts1 = wt0 + 2048;                     // 9*64*64    = 36864
    short* wts2 = wts1 + 36864;                   // 9*128*64   = 73728
    short* wts3 = wts2 + 73728;                   // 9*128*128  = 147456
    short* wts4 = wts3 + 147456;                  // 9*256*128  = 294912
    short* wts5 = wts4 + 294912;                  // 9*256*256  = 589824
    const size_t WT_HW = 2048 + 36864 + 73728 + 147456 + 294912 + 589824;
    const size_t fixed_bytes = WT_HW * 2;

    int Bc = B;
    while (Bc > 2 && fixed_bytes + (size_t)Bc * 2 * 65536 * 2 > ws_size) Bc >>= 1;
    if (Bc < 2) Bc = 2;

    ushort* bufA = (ushort*)((short*)d_ws + WT_HW);
    ushort* bufB = bufA + (size_t)Bc * 65536;

    // ---- weight transforms (every launch; ws is re-poisoned) ----
    wtransform0<<<(64 * 32 + 255) / 256, 256, 0, stream>>>(w0, wt0);
    wtransform_lin<<<(9 * 64 * 64 + 255) / 256, 256, 0, stream>>>(w1, wts1, 64, 64);
    wtransform_lin<<<(9 * 128 * 64 + 255) / 256, 256, 0, stream>>>(w2, wts2, 128, 64);
    wtransform_lin<<<(9 * 128 * 128 + 255) / 256, 256, 0, stream>>>(w3, wts3, 128, 128);
    wtransform_lin<<<(9 * 256 * 128 + 255) / 256, 256, 0, stream>>>(w4, wts4, 256, 128);
    wtransform_lin<<<(9 * 256 * 256 + 255) / 256, 256, 0, stream>>>(w5, wts5, 256, 256);

    for (int cb0 = 0; cb0 < B; cb0 += Bc) {
        const float* xc = x + (size_t)cb0 * 3 * 32 * 32;
        const int* tidc = tid + cb0;
        float* outc = outp + (size_t)cb0 * 5;

        // conv0: 3->64 @32x32 -> bufA [Bc][8][32][32][8]
        conv0_mfma<<<Bc * 2, 256, 0, stream>>>(xc, wt0, b0, bufA);
        // conv1+pool: 64->64 @32x32 -> bufB [Bc][8][16][16][8]
        conv_so<64, 64, 32, 32, 8, 1, true><<<Bc * 4, 256, 0, stream>>>(bufA, wts1, b1, bufB);
        // conv2: 64->128 @16x16 -> bufA [Bc][16][16][16][8]
        conv_so<64, 128, 16, 16, 8, 2, false><<<Bc * 2, 256, 0, stream>>>(bufB, wts2, b2, bufA);
        // conv3+pool: 128->128 @16x16 -> bufB [Bc][16][8][8][8]
        conv_so<128, 128, 16, 16, 8, 2, true><<<Bc * 2, 256, 0, stream>>>(bufA, wts3, b3, bufB);
        // conv4: 128->256 @8x8 -> bufA [Bc][32][8][8][8]
        conv_so<128, 256, 8, 8, 8, 4, false><<<Bc, 256, 0, stream>>>(bufB, wts4, b4, bufA);
        // conv5+pool: 256->256 @8x8 -> bufB [Bc][32][4][4][8]
        conv_so<256, 256, 8, 8, 8, 4, true><<<Bc, 256, 0, stream>>>(bufA, wts5, b5, bufB);
        // classifier
        classifier_k<<<(Bc * 5 * 64 + 255) / 256, 256, 0, stream>>>(bufB, tidc, cw, cb, outc, Bc);
    }
}